// Round 1
// baseline (595.607 us; speedup 1.0000x reference)
//
#include <hip/hip_runtime.h>

// Problem constants (B,H,W) = (16,512,512); upsample x2.
#define BATCH 16
#define HIN   512
#define WIN   512
#define HOUT  1024
#define WOUT  1024

// d_out layout: out[16,3,1024,1024] | x_mask[16,1,1024,1024] | y_mask[16,1,1024,1024]
#define OUT_ELEMS   ((size_t)BATCH * 3 * HOUT * WOUT)
#define MASK_ELEMS  ((size_t)BATCH * HOUT * WOUT)

typedef float f4 __attribute__((ext_vector_type(4)));

static __device__ __forceinline__ f4 relu4(f4 v) {
    v.x = fmaxf(v.x, 0.0f); v.y = fmaxf(v.y, 0.0f);
    v.z = fmaxf(v.z, 0.0f); v.w = fmaxf(v.w, 0.0f);
    return v;
}

// Block = 256 threads: half (tx>>7) selects even/odd output row of the pair,
// lane (tx&127) covers 8 output pixels. Grid = (HOUT/2, BATCH).
// Row pair (2r, 2r+1) shares input mask row r -> L1/L2 reuse within block.
__global__ __launch_bounds__(256) void fused_upsample_conv_kernel(
    const float* __restrict__ mask,   // (16,2,512,512)
    const float* __restrict__ xl,     // (16,3,1024,1024)
    const float* __restrict__ yl,     // (16,3,1024,1024)
    const float* __restrict__ cw,     // (3,3) row-major: cw[o*3+i]
    const float* __restrict__ cb,     // (3,)
    float* __restrict__ out)
{
    const int tx   = threadIdx.x;
    const int half = tx >> 7;           // 0 = even output row, 1 = odd
    const int lane = tx & 127;          // 8 px each -> 1024-wide row
    const int r    = blockIdx.x;        // input row base; output rows 2r, 2r+1
    const int b    = blockIdx.y;
    const int oh   = 2 * r + half;

    // ---- vertical (row) bilinear: half-pixel centers, clamped edges ----
    int rA, rB; float wyA, wyB;
    if (half) { rA = r;                   rB = (r + 1 < HIN) ? r + 1 : HIN - 1; wyA = 0.75f; wyB = 0.25f; }
    else      { rA = (r > 0) ? r - 1 : 0; rB = r;                               wyA = 0.25f; wyB = 0.75f; }

    // ---- horizontal stencil: 8 outputs ow0..ow0+7 need input cols 4*lane-1 .. 4*lane+4 ----
    const int c0 = lane * 4;                       // float4-aligned
    const int cL = (c0 > 0) ? c0 - 1 : 0;          // clamped left neighbor
    const int cR = (c0 + 4 < WIN) ? c0 + 4 : WIN - 1; // clamped right neighbor

    const size_t mplane = (size_t)HIN * WIN;
    const float* pA0 = mask + ((size_t)b * 2 + 0) * mplane + (size_t)rA * WIN;
    const float* pB0 = mask + ((size_t)b * 2 + 0) * mplane + (size_t)rB * WIN;
    const float* pA1 = mask + ((size_t)b * 2 + 1) * mplane + (size_t)rA * WIN;
    const float* pB1 = mask + ((size_t)b * 2 + 1) * mplane + (size_t)rB * WIN;

    // channel 0 (x_mask): vertical lerp of 6 stencil columns
    const f4    qA0 = *(const f4*)(pA0 + c0);
    const f4    qB0 = *(const f4*)(pB0 + c0);
    const float vL0 = wyA * pA0[cL] + wyB * pB0[cL];
    const float vR0 = wyA * pA0[cR] + wyB * pB0[cR];
    const f4    v0  = wyA * qA0 + wyB * qB0;

    // channel 1 (y_mask)
    const f4    qA1 = *(const f4*)(pA1 + c0);
    const f4    qB1 = *(const f4*)(pB1 + c0);
    const float vL1 = wyA * pA1[cL] + wyB * pB1[cL];
    const float vR1 = wyA * pA1[cR] + wyB * pB1[cR];
    const f4    v1  = wyA * qA1 + wyB * qB1;

    // ---- horizontal lerp -> 8 mask values per channel ----
    // out col 2m   : 0.25*v[m-1] + 0.75*v[m]
    // out col 2m+1 : 0.75*v[m]   + 0.25*v[m+1]
    f4 xm0, xm1, ym0, ym1;
    xm0.x = 0.25f*vL0  + 0.75f*v0.x;  xm0.y = 0.75f*v0.x + 0.25f*v0.y;
    xm0.z = 0.25f*v0.x + 0.75f*v0.y;  xm0.w = 0.75f*v0.y + 0.25f*v0.z;
    xm1.x = 0.25f*v0.y + 0.75f*v0.z;  xm1.y = 0.75f*v0.z + 0.25f*v0.w;
    xm1.z = 0.25f*v0.z + 0.75f*v0.w;  xm1.w = 0.75f*v0.w + 0.25f*vR0;

    ym0.x = 0.25f*vL1  + 0.75f*v1.x;  ym0.y = 0.75f*v1.x + 0.25f*v1.y;
    ym0.z = 0.25f*v1.x + 0.75f*v1.y;  ym0.w = 0.75f*v1.y + 0.25f*v1.z;
    ym1.x = 0.25f*v1.y + 0.75f*v1.z;  ym1.y = 0.75f*v1.z + 0.25f*v1.w;
    ym1.z = 0.25f*v1.z + 0.75f*v1.w;  ym1.w = 0.75f*v1.w + 0.25f*vR1;

    // ---- conv weights/bias (wave-uniform, cached) ----
    const float w00 = cw[0], w01 = cw[1], w02 = cw[2];
    const float w10 = cw[3], w11 = cw[4], w12 = cw[5];
    const float w20 = cw[6], w21 = cw[7], w22 = cw[8];
    const float b0 = cb[0], b1 = cb[1], b2 = cb[2];

    const size_t oplane = (size_t)HOUT * WOUT;
    const size_t rowoff = (size_t)oh * WOUT + (size_t)lane * 8;

    const float* xb = xl + ((size_t)b * 3) * oplane + rowoff;
    const float* yb = yl + ((size_t)b * 3) * oplane + rowoff;

    // ---- streamed (zero-reuse) xl/yl loads: nontemporal ----
    const f4 x00 = __builtin_nontemporal_load((const f4*)(xb + 0 * oplane));
    const f4 x01 = __builtin_nontemporal_load((const f4*)(xb + 0 * oplane) + 1);
    const f4 x10 = __builtin_nontemporal_load((const f4*)(xb + 1 * oplane));
    const f4 x11 = __builtin_nontemporal_load((const f4*)(xb + 1 * oplane) + 1);
    const f4 x20 = __builtin_nontemporal_load((const f4*)(xb + 2 * oplane));
    const f4 x21 = __builtin_nontemporal_load((const f4*)(xb + 2 * oplane) + 1);
    const f4 y00 = __builtin_nontemporal_load((const f4*)(yb + 0 * oplane));
    const f4 y01 = __builtin_nontemporal_load((const f4*)(yb + 0 * oplane) + 1);
    const f4 y10 = __builtin_nontemporal_load((const f4*)(yb + 1 * oplane));
    const f4 y11 = __builtin_nontemporal_load((const f4*)(yb + 1 * oplane) + 1);
    const f4 y20 = __builtin_nontemporal_load((const f4*)(yb + 2 * oplane));
    const f4 y21 = __builtin_nontemporal_load((const f4*)(yb + 2 * oplane) + 1);

    // fused_i = xm * xl_i + ym * yl_i
    const f4 f00 = xm0 * x00 + ym0 * y00;
    const f4 f01 = xm1 * x01 + ym1 * y01;
    const f4 f10 = xm0 * x10 + ym0 * y10;
    const f4 f11 = xm1 * x11 + ym1 * y11;
    const f4 f20 = xm0 * x20 + ym0 * y20;
    const f4 f21 = xm1 * x21 + ym1 * y21;

    // out_o = relu(w_o0*f0 + w_o1*f1 + w_o2*f2 + b_o)
    const f4 o00 = relu4(w00*f00 + w01*f10 + w02*f20 + b0);
    const f4 o01 = relu4(w00*f01 + w01*f11 + w02*f21 + b0);
    const f4 o10 = relu4(w10*f00 + w11*f10 + w12*f20 + b1);
    const f4 o11 = relu4(w10*f01 + w11*f11 + w12*f21 + b1);
    const f4 o20 = relu4(w20*f00 + w21*f10 + w22*f20 + b2);
    const f4 o21 = relu4(w20*f01 + w21*f11 + w22*f21 + b2);

    // ---- streamed stores: nontemporal ----
    float* ob = out + ((size_t)b * 3) * oplane + rowoff;
    __builtin_nontemporal_store(o00, (f4*)(ob + 0 * oplane));
    __builtin_nontemporal_store(o01, (f4*)(ob + 0 * oplane) + 1);
    __builtin_nontemporal_store(o10, (f4*)(ob + 1 * oplane));
    __builtin_nontemporal_store(o11, (f4*)(ob + 1 * oplane) + 1);
    __builtin_nontemporal_store(o20, (f4*)(ob + 2 * oplane));
    __builtin_nontemporal_store(o21, (f4*)(ob + 2 * oplane) + 1);

    float* xmp = out + OUT_ELEMS + (size_t)b * oplane + rowoff;
    float* ymp = out + OUT_ELEMS + MASK_ELEMS + (size_t)b * oplane + rowoff;
    __builtin_nontemporal_store(xm0, (f4*)xmp);
    __builtin_nontemporal_store(xm1, (f4*)xmp + 1);
    __builtin_nontemporal_store(ym0, (f4*)ymp);
    __builtin_nontemporal_store(ym1, (f4*)ymp + 1);
}

extern "C" void kernel_launch(void* const* d_in, const int* in_sizes, int n_in,
                              void* d_out, int out_size, void* d_ws, size_t ws_size,
                              hipStream_t stream) {
    const float* mask = (const float*)d_in[0];
    const float* xl   = (const float*)d_in[1];
    const float* yl   = (const float*)d_in[2];
    const float* cw   = (const float*)d_in[3];
    const float* cb   = (const float*)d_in[4];
    float* out = (float*)d_out;

    dim3 grid(HOUT / 2, BATCH);   // one block per (output row pair, batch)
    dim3 block(256);              // 2 rows x 128 threads x 8 px = 1024-wide
    fused_upsample_conv_kernel<<<grid, block, 0, stream>>>(mask, xl, yl, cw, cb, out);
}

// Round 2
// 580.265 us; speedup vs baseline: 1.0264x; 1.0264x over previous
//
#include <hip/hip_runtime.h>

// Problem constants (B,H,W) = (16,512,512); upsample x2.
#define BATCH 16
#define HIN   512
#define WIN   512
#define HOUT  1024
#define WOUT  1024

// d_out layout: out[16,3,1024,1024] | x_mask[16,1,1024,1024] | y_mask[16,1,1024,1024]
#define OUT_ELEMS   ((size_t)BATCH * 3 * HOUT * WOUT)
#define MASK_ELEMS  ((size_t)BATCH * HOUT * WOUT)

typedef float f4 __attribute__((ext_vector_type(4)));

static __device__ __forceinline__ f4 relu4(f4 v) {
    v.x = fmaxf(v.x, 0.0f); v.y = fmaxf(v.y, 0.0f);
    v.z = fmaxf(v.z, 0.0f); v.w = fmaxf(v.w, 0.0f);
    return v;
}

// Wave-specialized: block = 512 threads = 8 waves, one (input row r -> output
// rows 2r,2r+1) x batch per block. Waves 0-5: one xl/yl plane-row each
// (p = w%3, hr = w/3) -- 2 copy-like read streams per wave. Waves 6-7: the
// bilinear mask stencil (channel w-6). Exchange through LDS (40 KiB), then
// each wave drains exactly one contiguous output stream.
__global__ __launch_bounds__(512, 4) void fused_upsample_conv_kernel(
    const float* __restrict__ mask,   // (16,2,512,512)
    const float* __restrict__ xl,     // (16,3,1024,1024)
    const float* __restrict__ yl,     // (16,3,1024,1024)
    const float* __restrict__ cw,     // (3,3) row-major: cw[o*3+i]
    const float* __restrict__ cb,     // (3,)
    float* __restrict__ out)
{
    __shared__ float xm_l[2][WOUT];       // 8 KiB  upsampled x-mask, 2 rows
    __shared__ float ym_l[2][WOUT];       // 8 KiB  upsampled y-mask, 2 rows
    __shared__ float Fs[3][2][WOUT];      // 24 KiB fused = xm*xl + ym*yl

    const int tx = threadIdx.x;
    const int w  = tx >> 6;               // wave 0..7
    const int l  = tx & 63;               // lane
    const int r  = blockIdx.x;            // input row; output rows 2r, 2r+1
    const int b  = blockIdx.y;

    const size_t oplane = (size_t)HOUT * WOUT;
    const size_t mplane = (size_t)HIN * WIN;

    const int p  = w % 3;                 // plane (waves 0-5)
    const int hr = (w < 6) ? (w / 3) : 0; // row-of-pair
    const int oh = 2 * r + hr;

    // Plane waves stage their row in registers across the barrier.
    f4 xv0, xv1, xv2, xv3, yv0, yv1, yv2, yv3;

    // ---------------- phase 0/1: loads + mask stencil ----------------
    if (w < 6) {
        // px for lane l, chunk k: k*256 + l*4  (1 KiB contiguous per instr)
        const float* xp = xl + ((size_t)b * 3 + p) * oplane + (size_t)oh * WOUT;
        const float* yp = yl + ((size_t)b * 3 + p) * oplane + (size_t)oh * WOUT;
        xv0 = __builtin_nontemporal_load((const f4*)(xp +   0) + l);
        xv1 = __builtin_nontemporal_load((const f4*)(xp + 256) + l);
        xv2 = __builtin_nontemporal_load((const f4*)(xp + 512) + l);
        xv3 = __builtin_nontemporal_load((const f4*)(xp + 768) + l);
        yv0 = __builtin_nontemporal_load((const f4*)(yp +   0) + l);
        yv1 = __builtin_nontemporal_load((const f4*)(yp + 256) + l);
        yv2 = __builtin_nontemporal_load((const f4*)(yp + 512) + l);
        yv3 = __builtin_nontemporal_load((const f4*)(yp + 768) + l);
    } else {
        const int ch = w - 6;             // 0 -> x-mask, 1 -> y-mask
        const float* mp = mask + ((size_t)b * 2 + ch) * mplane;
        const int rm = (r > 0) ? r - 1 : 0;
        const int rp = (r + 1 < HIN) ? r + 1 : HIN - 1;
        const float* rowm = mp + (size_t)rm * WIN;
        const float* row0 = mp + (size_t)r  * WIN;
        const float* rowp = mp + (size_t)rp * WIN;

        // lane covers input cols c0..c0+7 -> output cols 16l..16l+15
        const int c0 = l * 8;
        const int cL = (c0 > 0) ? c0 - 1 : 0;
        const int cR = (c0 + 8 < WIN) ? c0 + 8 : WIN - 1;

        const f4 ma0 = *(const f4*)(rowm + c0), ma1 = *(const f4*)(rowm + c0 + 4);
        const f4 za0 = *(const f4*)(row0 + c0), za1 = *(const f4*)(row0 + c0 + 4);
        const f4 pa0 = *(const f4*)(rowp + c0), pa1 = *(const f4*)(rowp + c0 + 4);
        const float mL = rowm[cL], mR = rowm[cR];
        const float zL = row0[cL], zR = row0[cR];
        const float pL = rowp[cL], pR = rowp[cR];

        float* base = ch ? &ym_l[0][0] : &xm_l[0][0];

        // two vertical lerps (even: 0.25*up+0.75*cur, odd: 0.75*cur+0.25*down),
        // then horizontal lerp -> 16 output cols per lane per row.
        #pragma unroll
        for (int rr = 0; rr < 2; ++rr) {
            f4 va, vb; float vL, vR;
            if (rr == 0) {
                va = 0.25f * ma0 + 0.75f * za0;  vb = 0.25f * ma1 + 0.75f * za1;
                vL = 0.25f * mL  + 0.75f * zL;   vR = 0.25f * mR  + 0.75f * zR;
            } else {
                va = 0.75f * za0 + 0.25f * pa0;  vb = 0.75f * za1 + 0.25f * pa1;
                vL = 0.75f * zL  + 0.25f * pL;   vR = 0.75f * zR  + 0.25f * pR;
            }
            f4 o0, o1, o2, o3;
            o0.x = 0.25f*vL   + 0.75f*va.x;  o0.y = 0.75f*va.x + 0.25f*va.y;
            o0.z = 0.25f*va.x + 0.75f*va.y;  o0.w = 0.75f*va.y + 0.25f*va.z;
            o1.x = 0.25f*va.y + 0.75f*va.z;  o1.y = 0.75f*va.z + 0.25f*va.w;
            o1.z = 0.25f*va.z + 0.75f*va.w;  o1.w = 0.75f*va.w + 0.25f*vb.x;
            o2.x = 0.25f*va.w + 0.75f*vb.x;  o2.y = 0.75f*vb.x + 0.25f*vb.y;
            o2.z = 0.25f*vb.x + 0.75f*vb.y;  o2.w = 0.75f*vb.y + 0.25f*vb.z;
            o3.x = 0.25f*vb.y + 0.75f*vb.z;  o3.y = 0.75f*vb.z + 0.25f*vb.w;
            o3.z = 0.25f*vb.z + 0.75f*vb.w;  o3.w = 0.75f*vb.w + 0.25f*vR;
            float* d = base + rr * WOUT + l * 16;
            *(f4*)(d +  0) = o0;  *(f4*)(d +  4) = o1;
            *(f4*)(d +  8) = o2;  *(f4*)(d + 12) = o3;
        }
    }

    __syncthreads();   // masks in LDS

    // ---------------- phase 2: fuse into LDS ----------------
    if (w < 6) {
        const float* mx = &xm_l[hr][0];
        const float* my = &ym_l[hr][0];
        float* fd = &Fs[p][hr][0];
        const int c = l * 4;
        *(f4*)(fd + c +   0) = (*(const f4*)(mx + c +   0)) * xv0 + (*(const f4*)(my + c +   0)) * yv0;
        *(f4*)(fd + c + 256) = (*(const f4*)(mx + c + 256)) * xv1 + (*(const f4*)(my + c + 256)) * yv1;
        *(f4*)(fd + c + 512) = (*(const f4*)(mx + c + 512)) * xv2 + (*(const f4*)(my + c + 512)) * yv2;
        *(f4*)(fd + c + 768) = (*(const f4*)(mx + c + 768)) * xv3 + (*(const f4*)(my + c + 768)) * yv3;
    }

    __syncthreads();   // fused planes in LDS

    // ---------------- phase 3: one contiguous output stream per wave ----------------
    if (w < 6) {
        // wave (p,hr) -> out channel p, row oh
        const float w0 = cw[p * 3 + 0], w1 = cw[p * 3 + 1], w2 = cw[p * 3 + 2];
        const float bo = cb[p];
        float* op = out + ((size_t)b * 3 + p) * oplane + (size_t)oh * WOUT;
        const float* F0 = &Fs[0][hr][0];
        const float* F1 = &Fs[1][hr][0];
        const float* F2 = &Fs[2][hr][0];
        #pragma unroll
        for (int k = 0; k < 4; ++k) {
            const int c = k * 256 + l * 4;
            const f4 a0 = *(const f4*)(F0 + c);
            const f4 a1 = *(const f4*)(F1 + c);
            const f4 a2 = *(const f4*)(F2 + c);
            const f4 o  = relu4(w0 * a0 + w1 * a1 + w2 * a2 + bo);
            __builtin_nontemporal_store(o, (f4*)(op + c));
        }
    } else {
        // wave 6 -> x_mask rows 2r,2r+1 ; wave 7 -> y_mask rows 2r,2r+1
        const int ch = w - 6;
        const float* src = ch ? &ym_l[0][0] : &xm_l[0][0];
        float* op = out + OUT_ELEMS + (size_t)ch * MASK_ELEMS
                  + (size_t)b * oplane + (size_t)(2 * r) * WOUT;
        #pragma unroll
        for (int rr = 0; rr < 2; ++rr) {
            #pragma unroll
            for (int k = 0; k < 4; ++k) {
                const int c = k * 256 + l * 4;
                const f4 v = *(const f4*)(src + rr * WOUT + c);
                __builtin_nontemporal_store(v, (f4*)(op + rr * WOUT + c));
            }
        }
    }
}

extern "C" void kernel_launch(void* const* d_in, const int* in_sizes, int n_in,
                              void* d_out, int out_size, void* d_ws, size_t ws_size,
                              hipStream_t stream) {
    const float* mask = (const float*)d_in[0];
    const float* xl   = (const float*)d_in[1];
    const float* yl   = (const float*)d_in[2];
    const float* cw   = (const float*)d_in[3];
    const float* cb   = (const float*)d_in[4];
    float* out = (float*)d_out;

    dim3 grid(HIN, BATCH);    // one block per (input row -> output row pair, batch)
    dim3 block(512);          // 8 waves: 6 plane waves + 2 mask waves
    fused_upsample_conv_kernel<<<grid, block, 0, stream>>>(mask, xl, yl, cw, cb, out);
}